// Round 2
// baseline (123.774 us; speedup 1.0000x reference)
//
#include <hip/hip_runtime.h>
#include <hip/hip_bf16.h>
#include <math.h>

// Problem constants
#define DIM   512
#define NTR   16384
#define NT    8192
#define NCLS  16
#define NROWS (NTR + NT)   // 24576 projection rows

// r15: k moved from LDS to L2 (quad-uniform global loads), kq stored SoA
// (two planes) so logits use v_pk_fma_f32, pack uses v_cvt_pk_bf16_f32.
// Inner loop is now 1 ds_read + 4 VMEM + ~92 cy VALU (exp-dominated).
// r14: atomic flush -> split-K partials (2.23M contended atomics were
// first-order; measured -12 us).
// Budget model from r14 counters: ~82 us harness ws-fill (2x41 us
// fillBufferAligned, untouchable) + prep ~9.5 (50MB read, near roofline)
// + simmain ~14 + finalize ~2 + gaps.
#define JS     16                  // j-splits
#define JC     (NTR / JS)          // 1024 j per chunk
#define STEPS  (JC / 32)           // 32 K-steps (32 j each) per wave
#define NSTEPS (NTR / 32)          // 512 global K-steps

#define PROJ_BLOCKS (NROWS / 16)          // 1536 (16 rows/block, 4/wave)
#define PREP_BLOCKS ((NSTEPS * 64) / 256) // 128 (y-bake only)

// ws layout (floats): kq plane0 [24576] | kq plane1 [24576] |
//                     yfh (bf16 A-frag plane, 262144 shorts) |
//                     npart [JS][8192][16] | dpart [JS][8192]
#define WS_KQ_F    (NROWS * 2)           // 49152 (two SoA planes)
#define WS_YFH_S   (NSTEPS * 64 * 8)     // 262144 shorts (512 KB)
#define WS_NPART_F (JS * NT * NCLS)      // 2097152 (8 MB)
#define WS_DPART_F (JS * NT)             // 131072 (512 KB)

typedef __attribute__((ext_vector_type(8))) short short8;
typedef __attribute__((ext_vector_type(4))) float f32x4;
typedef __attribute__((ext_vector_type(2))) float f32x2;
typedef __attribute__((ext_vector_type(4))) unsigned int uint4v;

static __device__ __forceinline__ short f2bf(float f) {   // RNE (prep only)
    unsigned u = __float_as_uint(f);
    return (short)((u + 0x7FFFu + ((u >> 16) & 1u)) >> 16);
}
static __device__ __forceinline__ f32x2 mk2(float x, float y) {
    f32x2 r; r[0] = x; r[1] = y; return r;
}
// packed dual-FMA / dual-MUL (CDNA v_pk_fma_f32 / v_pk_mul_f32)
static __device__ __forceinline__ f32x2 pk_fma(f32x2 a, f32x2 b, f32x2 c) {
    f32x2 d;
    asm("v_pk_fma_f32 %0, %1, %2, %3" : "=v"(d) : "v"(a), "v"(b), "v"(c));
    return d;
}
static __device__ __forceinline__ f32x2 pk_mul(f32x2 a, f32x2 b) {
    f32x2 d;
    asm("v_pk_mul_f32 %0, %1, %2" : "=v"(d) : "v"(a), "v"(b));
    return d;
}
// packed f32x2 -> bf16x2 (lo = first operand), replaces 3-op perm trick
static __device__ __forceinline__ unsigned cvtpk(float a, float b) {
    unsigned d;
    asm("v_cvt_pk_bf16_f32 %0, %1, %2" : "=v"(d) : "v"(a), "v"(b));
    return d;
}

// ---------------------------------------------------------------------------
// Kernel 1 (fused prep): blocks [0,1536) = projection (4 rows/wave, 8
// independent loads + 8 parallel shuffle-reduce chains), now stored SoA
// (plane0 = first component, plane1 = second); blocks [1536,1664) = ytr^T
// bf16 bake in MFMA A-frag order. NO cross-block fences.
// ---------------------------------------------------------------------------
__global__ __launch_bounds__(256) void prep_kernel(
    const float* __restrict__ xtr, const float* __restrict__ xt,
    const float* __restrict__ A, const float* __restrict__ ytr,
    float* __restrict__ kq, short* __restrict__ yfh)
{
    const int b = blockIdx.x;
    if (b < PROJ_BLOCKS) {
        const int wave = threadIdx.x >> 6;
        const int lane = threadIdx.x & 63;
        const int row0 = b * 16 + wave * 4;

        const float* xp[4];
#pragma unroll
        for (int r = 0; r < 4; ++r) {
            const int row = row0 + r;
            xp[r] = (row < NTR) ? (xtr + (size_t)row * DIM)
                                : (xt + (size_t)(row - NTR) * DIM);
        }
        float a0[4] = {0.f, 0.f, 0.f, 0.f}, a1[4] = {0.f, 0.f, 0.f, 0.f};
#pragma unroll
        for (int t = 0; t < 2; ++t) {
            const int d = lane * 4 + t * 256;
            float4 A0 = *(const float4*)(A + 2 * d);       // A[d..d+1][0..1]
            float4 A1 = *(const float4*)(A + 2 * d + 4);   // A[d+2..d+3][0..1]
#pragma unroll
            for (int r = 0; r < 4; ++r) {
                float4 u = *(const float4*)(xp[r] + d);
                a0[r] += u.x * A0.x + u.y * A0.z + u.z * A1.x + u.w * A1.z;
                a1[r] += u.x * A0.y + u.y * A0.w + u.z * A1.y + u.w * A1.w;
            }
        }
#pragma unroll
        for (int off = 32; off >= 1; off >>= 1) {
#pragma unroll
            for (int r = 0; r < 4; ++r) {
                a0[r] += __shfl_xor(a0[r], off, 64);
                a1[r] += __shfl_xor(a1[r], off, 64);
            }
        }
        if (lane == 0) {   // SoA: plane0 then plane1
            *(float4*)(kq + row0)         = make_float4(a0[0], a0[1], a0[2], a0[3]);
            *(float4*)(kq + NROWS + row0) = make_float4(a1[0], a1[1], a1[2], a1[3]);
        }
    } else {
        const int idx = (b - PROJ_BLOCKS) * 256 + threadIdx.x;  // 0..32767
        const int l   = idx & 63;
        const int s   = idx >> 6;
        const int cls = l & 15;
        const int jb  = s * 32 + (l >> 4) * 8;
        short8 hi;
#pragma unroll
        for (int t = 0; t < 8; ++t)
            hi[t] = f2bf(ytr[(size_t)(jb + t) * NCLS + cls]);
        ((short8*)yfh)[idx] = hi;
    }
}

// ---------------------------------------------------------------------------
// Kernel 2: main. Grid (NT/128, JS) = (64, 16) = 1024 blocks of 512 threads
// (8 waves). Block stages only its y-chunk (32 KB bf16 A-frags) in LDS; k is
// read per-step straight from L2 (quad-uniform addresses coalesce to 64 B
// per instr; chunk is 8 KB, fully L2-resident; total extra L2 traffic
// ~67 MB ~ 2 us of L2 BW). Per step: 1 lane-contiguous ds_read_b128 (y) +
// 4 VMEM dwordx4 (k), 4 v_pk_mul + 4 v_pk_fma (logits, SoA planes),
// 8 raw v_exp_f32, 4 v_cvt_pk_bf16_f32, 2 MFMAs. Flush: plain coalesced
// split-K partial stores — no atomics, no fences.
// ---------------------------------------------------------------------------
__global__ __launch_bounds__(512) void simmain_kernel(
    const float* __restrict__ kq, const short* __restrict__ yfh,
    float* __restrict__ npart, float* __restrict__ dpart)
{
    __shared__ short8 ys[STEPS * 64];    // 32 KB bf16 y-frags (A-op order)

    const int tid  = threadIdx.x;        // 0..511
    const int wave = tid >> 6;           // 0..7
    const int lane = tid & 63;
    const int j0   = blockIdx.y * JC;

    const int i0   = (blockIdx.x * 8 + wave) * 16;
    const int m    = lane & 15;
    const int quad = lane >> 4;

    // q load first (overlaps staging latency); pre-scale by log2(e)
    const float q0 = kq[NTR + i0 + m]         * 1.4426950408889634f;
    const float q1 = kq[NROWS + NTR + i0 + m] * 1.4426950408889634f;
    const f32x2 q00 = mk2(q0, q0);
    const f32x2 q11 = mk2(q1, q1);

    {   // stage y only (2048 float4, 4/thread)
        const float4* ysrc = (const float4*)(yfh + (size_t)blockIdx.y * (STEPS * 64) * 8);
        float4* ydst = (float4*)ys;
#pragma unroll
        for (int p = 0; p < 4; ++p)
            ydst[tid + 512 * p] = ysrc[tid + 512 * p];
    }
    __syncthreads();

    f32x4 acc  = {0.f, 0.f, 0.f, 0.f};
    f32x4 acc2 = {0.f, 0.f, 0.f, 0.f};
    short8 ones;
#pragma unroll
    for (int t = 0; t < 8; ++t) ones[t] = (short)0x3F80;   // bf16 1.0

    const short8* __restrict__ yls = ys + lane;            // + s*64 per step
    const float* __restrict__ kq0 = kq + j0 + quad * 8;          // plane0
    const float* __restrict__ kq1 = kq + NROWS + j0 + quad * 8;  // plane1

#pragma unroll 2
    for (int s = 0; s < STEPS; ++s) {
        const short8 yh = yls[s * 64];          // lane-contiguous ds_read_b128
        // k from L2: quad-uniform dwordx4 loads, SoA planes
        const float4 a0 = *(const float4*)(kq0 + s * 32);
        const float4 b0 = *(const float4*)(kq0 + s * 32 + 4);
        const float4 a1 = *(const float4*)(kq1 + s * 32);
        const float4 b1 = *(const float4*)(kq1 + s * 32 + 4);

        // logits (packed): l = q0*k0[j] + q1*k1[j], 2 j per op
        const f32x2 l0 = pk_fma(q11, mk2(a1.x, a1.y), pk_mul(q00, mk2(a0.x, a0.y)));
        const f32x2 l1 = pk_fma(q11, mk2(a1.z, a1.w), pk_mul(q00, mk2(a0.z, a0.w)));
        const f32x2 l2 = pk_fma(q11, mk2(b1.x, b1.y), pk_mul(q00, mk2(b0.x, b0.y)));
        const f32x2 l3 = pk_fma(q11, mk2(b1.z, b1.w), pk_mul(q00, mk2(b0.z, b0.w)));

        const float e0 = __builtin_amdgcn_exp2f(l0[0]);
        const float e1 = __builtin_amdgcn_exp2f(l0[1]);
        const float e2 = __builtin_amdgcn_exp2f(l1[0]);
        const float e3 = __builtin_amdgcn_exp2f(l1[1]);
        const float e4 = __builtin_amdgcn_exp2f(l2[0]);
        const float e5 = __builtin_amdgcn_exp2f(l2[1]);
        const float e6 = __builtin_amdgcn_exp2f(l3[0]);
        const float e7 = __builtin_amdgcn_exp2f(l3[1]);

        uint4v ep;
        ep[0] = cvtpk(e0, e1); ep[1] = cvtpk(e2, e3);
        ep[2] = cvtpk(e4, e5); ep[3] = cvtpk(e6, e7);
        const short8 eb = __builtin_bit_cast(short8, ep);

        acc  = __builtin_amdgcn_mfma_f32_16x16x32_bf16(yh,   eb, acc,  0, 0, 0);
        acc2 = __builtin_amdgcn_mfma_f32_16x16x32_bf16(ones, eb, acc2, 0, 0, 0);
    }

    // Flush: deterministic split-K partials, plain coalesced stores.
    float* np = npart + ((size_t)blockIdx.y * NT + (i0 + m)) * NCLS + quad * 4;
    *(float4*)np = make_float4(acc[0], acc[1], acc[2], acc[3]);
    if (quad == 0)
        dpart[blockIdx.y * NT + i0 + m] = acc2[0];
}

// ---------------------------------------------------------------------------
// Kernel 3: finalize — reduce JS split-K partials, divide by denominator.
// ---------------------------------------------------------------------------
__global__ __launch_bounds__(256) void finalize_kernel(
    const float* __restrict__ npart, const float* __restrict__ dpart,
    float* __restrict__ out)
{
    const int idx = blockIdx.x * 256 + threadIdx.x;   // < NT*NCLS
    const int i = idx >> 4;
    float n = 0.f, d = 0.f;
#pragma unroll
    for (int s = 0; s < JS; ++s) {
        n += npart[(size_t)s * (NT * NCLS) + idx];
        d += dpart[s * NT + i];
    }
    out[idx] = n / d;
}

// ---------------------------------------------------------------------------
extern "C" void kernel_launch(void* const* d_in, const int* in_sizes, int n_in,
                              void* d_out, int out_size, void* d_ws, size_t ws_size,
                              hipStream_t stream)
{
    const float* xtr = (const float*)d_in[0];   // [16384][512]
    const float* ytr = (const float*)d_in[1];   // [16384][16]
    const float* xt  = (const float*)d_in[2];   // [8192][512]
    const float* A   = (const float*)d_in[3];   // [512][2]
    float* out = (float*)d_out;                 // [8192][16]

    float* kq    = (float*)d_ws;                       // 49152 floats (SoA)
    short* yfh   = (short*)(kq + WS_KQ_F);             // 262144 shorts (512 KB)
    float* npart = (float*)(yfh + WS_YFH_S);           // 2097152 floats (8 MB)
    float* dpart = npart + WS_NPART_F;                 // 131072 floats (512 KB)

    prep_kernel<<<PROJ_BLOCKS + PREP_BLOCKS, 256, 0, stream>>>(
        xtr, xt, A, ytr, kq, yfh);
    simmain_kernel<<<dim3(NT / 128, JS), 512, 0, stream>>>(
        kq, yfh, npart, dpart);
    finalize_kernel<<<(NT * NCLS) / 256, 256, 0, stream>>>(npart, dpart, out);
}

// Round 3
// 109.847 us; speedup vs baseline: 1.1268x; 1.1268x over previous
//
#include <hip/hip_runtime.h>
#include <hip/hip_bf16.h>
#include <math.h>

// Problem constants
#define DIM   512
#define NTR   16384
#define NT    8192
#define NCLS  16
#define NROWS (NTR + NT)   // 24576 projection rows

// r16: r14's ALL-LDS k-loop restored (r15's quad-uniform L2 k-loads cost
// +12 us: 4x ~200cy dependent VMEM latency per step is not hideable at 4
// waves/SIMD; LDS broadcast reads were near-free). Kept from r15: SoA k
// planes -> v_pk_fma_f32 logits (16 ops -> 8) and v_cvt_pk_bf16_f32 pack
// (12 ops -> 4). Per-step VALU ~124 -> ~92 cy, exp (64 cy) now the floor.
// r14: atomic flush -> split-K partials (measured -12 us).
// Budget model: ~85 us harness ws-fill (2x ~42 us fillBufferAligned,
// untouchable) + prep ~9.5 + simmain ~11 (predicted) + finalize ~2 + gaps.
#define JS     16                  // j-splits
#define JC     (NTR / JS)          // 1024 j per chunk
#define STEPS  (JC / 32)           // 32 K-steps (32 j each) per wave
#define NSTEPS (NTR / 32)          // 512 global K-steps

#define PROJ_BLOCKS (NROWS / 16)          // 1536 (16 rows/block, 4/wave)
#define PREP_BLOCKS ((NSTEPS * 64) / 256) // 128 (y-bake only)

// ws layout (floats): kq plane0 [24576] | kq plane1 [24576] |
//                     yfh (bf16 A-frag plane, 262144 shorts) |
//                     npart [JS][8192][16] | dpart [JS][8192]
#define WS_KQ_F    (NROWS * 2)           // 49152 (two SoA planes)
#define WS_YFH_S   (NSTEPS * 64 * 8)     // 262144 shorts (512 KB)
#define WS_NPART_F (JS * NT * NCLS)      // 2097152 (8 MB)
#define WS_DPART_F (JS * NT)             // 131072 (512 KB)

typedef __attribute__((ext_vector_type(8))) short short8;
typedef __attribute__((ext_vector_type(4))) float f32x4;
typedef __attribute__((ext_vector_type(2))) float f32x2;
typedef __attribute__((ext_vector_type(4))) unsigned int uint4v;

static __device__ __forceinline__ short f2bf(float f) {   // RNE (prep only)
    unsigned u = __float_as_uint(f);
    return (short)((u + 0x7FFFu + ((u >> 16) & 1u)) >> 16);
}
static __device__ __forceinline__ f32x2 mk2(float x, float y) {
    f32x2 r; r[0] = x; r[1] = y; return r;
}
// packed dual-FMA / dual-MUL (CDNA v_pk_fma_f32 / v_pk_mul_f32)
static __device__ __forceinline__ f32x2 pk_fma(f32x2 a, f32x2 b, f32x2 c) {
    f32x2 d;
    asm("v_pk_fma_f32 %0, %1, %2, %3" : "=v"(d) : "v"(a), "v"(b), "v"(c));
    return d;
}
static __device__ __forceinline__ f32x2 pk_mul(f32x2 a, f32x2 b) {
    f32x2 d;
    asm("v_pk_mul_f32 %0, %1, %2" : "=v"(d) : "v"(a), "v"(b));
    return d;
}
// packed f32x2 -> bf16x2 (lo = first operand), replaces 3-op perm trick
static __device__ __forceinline__ unsigned cvtpk(float a, float b) {
    unsigned d;
    asm("v_cvt_pk_bf16_f32 %0, %1, %2" : "=v"(d) : "v"(a), "v"(b));
    return d;
}

// ---------------------------------------------------------------------------
// Kernel 1 (fused prep): blocks [0,1536) = projection (4 rows/wave, 8
// independent loads + 8 parallel shuffle-reduce chains), stored SoA
// (plane0 = first component, plane1 = second); blocks [1536,1664) = ytr^T
// bf16 bake in MFMA A-frag order. NO cross-block fences.
// ---------------------------------------------------------------------------
__global__ __launch_bounds__(256) void prep_kernel(
    const float* __restrict__ xtr, const float* __restrict__ xt,
    const float* __restrict__ A, const float* __restrict__ ytr,
    float* __restrict__ kq, short* __restrict__ yfh)
{
    const int b = blockIdx.x;
    if (b < PROJ_BLOCKS) {
        const int wave = threadIdx.x >> 6;
        const int lane = threadIdx.x & 63;
        const int row0 = b * 16 + wave * 4;

        const float* xp[4];
#pragma unroll
        for (int r = 0; r < 4; ++r) {
            const int row = row0 + r;
            xp[r] = (row < NTR) ? (xtr + (size_t)row * DIM)
                                : (xt + (size_t)(row - NTR) * DIM);
        }
        float a0[4] = {0.f, 0.f, 0.f, 0.f}, a1[4] = {0.f, 0.f, 0.f, 0.f};
#pragma unroll
        for (int t = 0; t < 2; ++t) {
            const int d = lane * 4 + t * 256;
            float4 A0 = *(const float4*)(A + 2 * d);       // A[d..d+1][0..1]
            float4 A1 = *(const float4*)(A + 2 * d + 4);   // A[d+2..d+3][0..1]
#pragma unroll
            for (int r = 0; r < 4; ++r) {
                float4 u = *(const float4*)(xp[r] + d);
                a0[r] += u.x * A0.x + u.y * A0.z + u.z * A1.x + u.w * A1.z;
                a1[r] += u.x * A0.y + u.y * A0.w + u.z * A1.y + u.w * A1.w;
            }
        }
#pragma unroll
        for (int off = 32; off >= 1; off >>= 1) {
#pragma unroll
            for (int r = 0; r < 4; ++r) {
                a0[r] += __shfl_xor(a0[r], off, 64);
                a1[r] += __shfl_xor(a1[r], off, 64);
            }
        }
        if (lane == 0) {   // SoA: plane0 then plane1
            *(float4*)(kq + row0)         = make_float4(a0[0], a0[1], a0[2], a0[3]);
            *(float4*)(kq + NROWS + row0) = make_float4(a1[0], a1[1], a1[2], a1[3]);
        }
    } else {
        const int idx = (b - PROJ_BLOCKS) * 256 + threadIdx.x;  // 0..32767
        const int l   = idx & 63;
        const int s   = idx >> 6;
        const int cls = l & 15;
        const int jb  = s * 32 + (l >> 4) * 8;
        short8 hi;
#pragma unroll
        for (int t = 0; t < 8; ++t)
            hi[t] = f2bf(ytr[(size_t)(jb + t) * NCLS + cls]);
        ((short8*)yfh)[idx] = hi;
    }
}

// ---------------------------------------------------------------------------
// Kernel 2: main. Grid (NT/128, JS) = (64, 16) = 1024 blocks of 512 threads
// (8 waves). ALL-LDS K-loop: block stages its k-chunk (8 KB fp32, two SoA
// planes) and y-chunk (32 KB bf16 A-frags) once; the 32-step loop touches
// only LDS + VALU. Per step: 1 lane-contiguous ds_read_b128 (y) + 4
// quad-broadcast b128 (k, 2 per plane), 4 v_pk_mul + 4 v_pk_fma (logits),
// 8 raw v_exp_f32, 4 v_cvt_pk_bf16_f32, 2 MFMAs. Flush: plain coalesced
// split-K partial stores — no atomics, no fences.
// ---------------------------------------------------------------------------
__global__ __launch_bounds__(512) void simmain_kernel(
    const float* __restrict__ kq, const short* __restrict__ yfh,
    float* __restrict__ npart, float* __restrict__ dpart)
{
    __shared__ float  ks0[JC];           // 4 KB plane0
    __shared__ float  ks1[JC];           // 4 KB plane1
    __shared__ short8 ys[STEPS * 64];    // 32 KB bf16 y-frags (A-op order)

    const int tid  = threadIdx.x;        // 0..511
    const int wave = tid >> 6;           // 0..7
    const int lane = tid & 63;
    const int j0   = blockIdx.y * JC;

    const int i0   = (blockIdx.x * 8 + wave) * 16;
    const int m    = lane & 15;
    const int quad = lane >> 4;

    // q load first (overlaps staging latency); pre-scale by log2(e)
    const float q0 = kq[NTR + i0 + m]         * 1.4426950408889634f;
    const float q1 = kq[NROWS + NTR + i0 + m] * 1.4426950408889634f;
    const f32x2 q00 = mk2(q0, q0);
    const f32x2 q11 = mk2(q1, q1);

    {   // stage k (512 float4 over both planes, 1/thread) + y (4/thread)
        const float4* k0src = (const float4*)(kq + j0);
        const float4* k1src = (const float4*)(kq + NROWS + j0);
        if (tid < 256) ((float4*)ks0)[tid] = k0src[tid];
        else           ((float4*)ks1)[tid - 256] = k1src[tid - 256];
        const float4* ysrc = (const float4*)(yfh + (size_t)blockIdx.y * (STEPS * 64) * 8);
        float4* ydst = (float4*)ys;
#pragma unroll
        for (int p = 0; p < 4; ++p)
            ydst[tid + 512 * p] = ysrc[tid + 512 * p];
    }
    __syncthreads();

    f32x4 acc  = {0.f, 0.f, 0.f, 0.f};
    f32x4 acc2 = {0.f, 0.f, 0.f, 0.f};
    short8 ones;
#pragma unroll
    for (int t = 0; t < 8; ++t) ones[t] = (short)0x3F80;   // bf16 1.0

    const short8* __restrict__ yls = ys + lane;            // + s*64 per step
    const float* __restrict__ kx0 = ks0 + quad * 8;        // plane0
    const float* __restrict__ kx1 = ks1 + quad * 8;        // plane1

#pragma unroll 4
    for (int s = 0; s < STEPS; ++s) {
        const short8 yh = yls[s * 64];          // lane-contiguous ds_read_b128
        // k from LDS: quad-broadcast b128 reads, 2 per SoA plane
        const float4 a0 = *(const float4*)(kx0 + s * 32);
        const float4 b0 = *(const float4*)(kx0 + s * 32 + 4);
        const float4 a1 = *(const float4*)(kx1 + s * 32);
        const float4 b1 = *(const float4*)(kx1 + s * 32 + 4);

        // logits (packed): l = q0*k0[j] + q1*k1[j], 2 j per op
        const f32x2 l0 = pk_fma(q11, mk2(a1.x, a1.y), pk_mul(q00, mk2(a0.x, a0.y)));
        const f32x2 l1 = pk_fma(q11, mk2(a1.z, a1.w), pk_mul(q00, mk2(a0.z, a0.w)));
        const f32x2 l2 = pk_fma(q11, mk2(b1.x, b1.y), pk_mul(q00, mk2(b0.x, b0.y)));
        const f32x2 l3 = pk_fma(q11, mk2(b1.z, b1.w), pk_mul(q00, mk2(b0.z, b0.w)));

        const float e0 = __builtin_amdgcn_exp2f(l0[0]);
        const float e1 = __builtin_amdgcn_exp2f(l0[1]);
        const float e2 = __builtin_amdgcn_exp2f(l1[0]);
        const float e3 = __builtin_amdgcn_exp2f(l1[1]);
        const float e4 = __builtin_amdgcn_exp2f(l2[0]);
        const float e5 = __builtin_amdgcn_exp2f(l2[1]);
        const float e6 = __builtin_amdgcn_exp2f(l3[0]);
        const float e7 = __builtin_amdgcn_exp2f(l3[1]);

        uint4v ep;
        ep[0] = cvtpk(e0, e1); ep[1] = cvtpk(e2, e3);
        ep[2] = cvtpk(e4, e5); ep[3] = cvtpk(e6, e7);
        const short8 eb = __builtin_bit_cast(short8, ep);

        acc  = __builtin_amdgcn_mfma_f32_16x16x32_bf16(yh,   eb, acc,  0, 0, 0);
        acc2 = __builtin_amdgcn_mfma_f32_16x16x32_bf16(ones, eb, acc2, 0, 0, 0);
    }

    // Flush: deterministic split-K partials, plain coalesced stores.
    float* np = npart + ((size_t)blockIdx.y * NT + (i0 + m)) * NCLS + quad * 4;
    *(float4*)np = make_float4(acc[0], acc[1], acc[2], acc[3]);
    if (quad == 0)
        dpart[blockIdx.y * NT + i0 + m] = acc2[0];
}

// ---------------------------------------------------------------------------
// Kernel 3: finalize — reduce JS split-K partials, divide by denominator.
// ---------------------------------------------------------------------------
__global__ __launch_bounds__(256) void finalize_kernel(
    const float* __restrict__ npart, const float* __restrict__ dpart,
    float* __restrict__ out)
{
    const int idx = blockIdx.x * 256 + threadIdx.x;   // < NT*NCLS
    const int i = idx >> 4;
    float n = 0.f, d = 0.f;
#pragma unroll
    for (int s = 0; s < JS; ++s) {
        n += npart[(size_t)s * (NT * NCLS) + idx];
        d += dpart[s * NT + i];
    }
    out[idx] = n / d;
}

// ---------------------------------------------------------------------------
extern "C" void kernel_launch(void* const* d_in, const int* in_sizes, int n_in,
                              void* d_out, int out_size, void* d_ws, size_t ws_size,
                              hipStream_t stream)
{
    const float* xtr = (const float*)d_in[0];   // [16384][512]
    const float* ytr = (const float*)d_in[1];   // [16384][16]
    const float* xt  = (const float*)d_in[2];   // [8192][512]
    const float* A   = (const float*)d_in[3];   // [512][2]
    float* out = (float*)d_out;                 // [8192][16]

    float* kq    = (float*)d_ws;                       // 49152 floats (SoA)
    short* yfh   = (short*)(kq + WS_KQ_F);             // 262144 shorts (512 KB)
    float* npart = (float*)(yfh + WS_YFH_S);           // 2097152 floats (8 MB)
    float* dpart = npart + WS_NPART_F;                 // 131072 floats (512 KB)

    prep_kernel<<<PROJ_BLOCKS + PREP_BLOCKS, 256, 0, stream>>>(
        xtr, xt, A, ytr, kq, yfh);
    simmain_kernel<<<dim3(NT / 128, JS), 512, 0, stream>>>(
        kq, yfh, npart, dpart);
    finalize_kernel<<<(NT * NCLS) / 256, 256, 0, stream>>>(npart, dpart, out);
}